// Round 3
// baseline (727.684 us; speedup 1.0000x reference)
//
#include <hip/hip_runtime.h>
#include <math.h>

__device__ __forceinline__ float sigmf(float x) { return 1.0f / (1.0f + expf(-x)); }

// ---------------- conv1: x[3,168,300] -> out[128,41,74], k=8, s=4, relu ----------------
__global__ __launch_bounds__(256) void conv1_k(const float* __restrict__ x,
                                               const float* __restrict__ w,
                                               const float* __restrict__ b,
                                               float* __restrict__ out) {
    __shared__ float ws[192];
    const int co = blockIdx.x / 12, chunk = blockIdx.x % 12;
    for (int i = threadIdx.x; i < 192; i += 256) ws[i] = w[co * 192 + i];
    __syncthreads();
    const int pix = chunk * 256 + (int)threadIdx.x;
    if (pix >= 41 * 74) return;
    const int oh = pix / 74, ow = pix % 74;
    const float* xp = x + oh * 4 * 300 + ow * 4;
    float acc = b[co];
    #pragma unroll
    for (int ci = 0; ci < 3; ci++) {
        #pragma unroll
        for (int kh = 0; kh < 8; kh++) {
            const float* row = xp + ci * (168 * 300) + kh * 300;
            const float* wr = ws + ci * 64 + kh * 8;
            #pragma unroll
            for (int kw = 0; kw < 8; kw++) acc = fmaf(row[kw], wr[kw], acc);
        }
    }
    out[co * 3034 + pix] = fmaxf(acc, 0.0f);
}

// ---------------- conv2: in[128,41,74] -> out[64,19,36], k=4, s=2, relu ----------------
__global__ __launch_bounds__(256) void conv2_k(const float* __restrict__ in,
                                               const float* __restrict__ w,
                                               const float* __restrict__ b,
                                               float* __restrict__ out) {
    __shared__ float ws[2048];
    const int co = blockIdx.x / 3, chunk = blockIdx.x % 3;
    for (int i = threadIdx.x; i < 2048; i += 256) ws[i] = w[co * 2048 + i];
    __syncthreads();
    const int pix = chunk * 256 + (int)threadIdx.x;
    if (pix >= 19 * 36) return;
    const int oh = pix / 36, ow = pix % 36;
    const float* base = in + oh * 2 * 74 + ow * 2;
    float acc = b[co];
    for (int ci = 0; ci < 128; ci++) {
        const float* ip = base + ci * 3034;
        const float* wc = ws + ci * 16;
        #pragma unroll
        for (int kh = 0; kh < 4; kh++) {
            const float* row = ip + kh * 74;
            const float* wr = wc + kh * 4;
            acc = fmaf(row[0], wr[0], acc);
            acc = fmaf(row[1], wr[1], acc);
            acc = fmaf(row[2], wr[2], acc);
            acc = fmaf(row[3], wr[3], acc);
        }
    }
    out[co * 684 + pix] = fmaxf(acc, 0.0f);
}

// ---------------- conv3: in[64,19,36] -> out[64,8,17], k=4, s=2, relu ----------------
__global__ __launch_bounds__(192) void conv3_k(const float* __restrict__ in,
                                               const float* __restrict__ w,
                                               const float* __restrict__ b,
                                               float* __restrict__ out) {
    __shared__ float ws[1024];
    const int co = blockIdx.x;
    for (int i = threadIdx.x; i < 1024; i += 192) ws[i] = w[co * 1024 + i];
    __syncthreads();
    const int pix = threadIdx.x;
    if (pix >= 8 * 17) return;
    const int oh = pix / 17, ow = pix % 17;
    const float* base = in + oh * 2 * 36 + ow * 2;
    float acc = b[co];
    for (int ci = 0; ci < 64; ci++) {
        const float* ip = base + ci * 684;
        const float* wc = ws + ci * 16;
        #pragma unroll
        for (int kh = 0; kh < 4; kh++) {
            const float* row = ip + kh * 36;
            const float* wr = wc + kh * 4;
            acc = fmaf(row[0], wr[0], acc);
            acc = fmaf(row[1], wr[1], acc);
            acc = fmaf(row[2], wr[2], acc);
            acc = fmaf(row[3], wr[3], acc);
        }
    }
    out[co * 136 + pix] = fmaxf(acc, 0.0f);
}

// ---------------- fused: GRU(18 steps) + attention + linear + LSTM + heads ----------------
__global__ __launch_bounds__(1024) void fused_k(
    const int* __restrict__ inst, const int* __restrict__ tx,
    const float* __restrict__ hx, const float* __restrict__ cx,
    const float* __restrict__ emb,
    const float* __restrict__ wih, const float* __restrict__ whh,
    const float* __restrict__ bih, const float* __restrict__ bhh,
    const float* __restrict__ attn_w, const float* __restrict__ attn_b,
    const float* __restrict__ time_emb,
    const float* __restrict__ lin_w, const float* __restrict__ lin_b,
    const float* __restrict__ lstm_wih, const float* __restrict__ lstm_whh,
    const float* __restrict__ lstm_bih, const float* __restrict__ lstm_bhh,
    const float* __restrict__ critic_w, const float* __restrict__ critic_b,
    const float* __restrict__ actor_w, const float* __restrict__ actor_b,
    const float* __restrict__ img, float* __restrict__ out) {

    __shared__ __align__(16) float h_s[256];
    __shared__ __align__(16) float wt_s[32];
    __shared__ __align__(16) float r_s[256], z_s[256], ig_s[256], hg_s[256];
    __shared__ __align__(16) float attn_s[320];
    __shared__ __align__(16) float av_s[680];
    __shared__ __align__(16) float feat_s[256];
    __shared__ __align__(16) float gates_s[1024];
    __shared__ __align__(16) float hx_s[256];
    __shared__ __align__(16) float f2_s[288];

    const int tid = threadIdx.x;
    if (tid < 256) { h_s[tid] = 0.0f; hx_s[tid] = hx[tid]; }
    __syncthreads();

    // ---- GRU over 18 tokens ----
    for (int t = 0; t < 18; t++) {
        if (tid < 32) wt_s[tid] = emb[inst[t] * 32 + tid];
        __syncthreads();
        if (tid < 768) {
            // gi = wih[tid,:] . wt + bih[tid]
            const float4* wr = reinterpret_cast<const float4*>(wih + tid * 32);
            const float4* c4 = reinterpret_cast<const float4*>(wt_s);
            float gi = 0.0f;
            #pragma unroll
            for (int q = 0; q < 8; q++) {
                float4 a = wr[q], c = c4[q];
                gi += a.x * c.x + a.y * c.y + a.z * c.z + a.w * c.w;
            }
            gi += bih[tid];
            // gh = whh[tid,:] . h + bhh[tid]
            const float4* hw = reinterpret_cast<const float4*>(whh + tid * 256);
            const float4* h4 = reinterpret_cast<const float4*>(h_s);
            float s0 = 0.f, s1 = 0.f, s2 = 0.f, s3 = 0.f;
            #pragma unroll
            for (int q = 0; q < 64; q += 4) {
                float4 a0 = hw[q + 0], c0 = h4[q + 0];
                float4 a1 = hw[q + 1], c1 = h4[q + 1];
                float4 a2 = hw[q + 2], c2 = h4[q + 2];
                float4 a3 = hw[q + 3], c3 = h4[q + 3];
                s0 += a0.x * c0.x + a0.y * c0.y + a0.z * c0.z + a0.w * c0.w;
                s1 += a1.x * c1.x + a1.y * c1.y + a1.z * c1.z + a1.w * c1.w;
                s2 += a2.x * c2.x + a2.y * c2.y + a2.z * c2.z + a2.w * c2.w;
                s3 += a3.x * c3.x + a3.y * c3.y + a3.z * c3.z + a3.w * c3.w;
            }
            float gh = ((s0 + s1) + (s2 + s3)) + bhh[tid];
            if (tid < 256)       r_s[tid]        = sigmf(gi + gh);
            else if (tid < 512)  z_s[tid - 256]  = sigmf(gi + gh);
            else               { ig_s[tid - 512] = gi; hg_s[tid - 512] = gh; }
        }
        __syncthreads();
        if (tid < 256) {
            float g = tanhf(ig_s[tid] + r_s[tid] * hg_s[tid]);
            h_s[tid] = (1.0f - z_s[tid]) * g + z_s[tid] * h_s[tid];
        }
        // next iteration's top __syncthreads() orders the h_s update
    }
    __syncthreads();

    // ---- attention rows: attn[320] = relu(attn_w @ instr + attn_b) ----
    if (tid < 320) {
        const float4* wr = reinterpret_cast<const float4*>(attn_w + tid * 256);
        const float4* h4 = reinterpret_cast<const float4*>(h_s);
        float s0 = 0.f, s1 = 0.f;
        #pragma unroll
        for (int q = 0; q < 64; q += 2) {
            float4 a0 = wr[q], c0 = h4[q];
            float4 a1 = wr[q + 1], c1 = h4[q + 1];
            s0 += a0.x * c0.x + a0.y * c0.y + a0.z * c0.z + a0.w * c0.w;
            s1 += a1.x * c1.x + a1.y * c1.y + a1.z * c1.z + a1.w * c1.w;
        }
        attn_s[tid] = fmaxf(s0 + s1 + attn_b[tid], 0.0f);
    }
    __syncthreads();

    // ---- attn_vecs[680]: sum_c attn[k,c] * img[c,h,w] ----
    if (tid < 680) {
        const int k = tid / 136, rem = tid % 136;
        const float* a = attn_s + k * 64;
        const float* ip = img + rem;
        float s0 = 0.f, s1 = 0.f;
        #pragma unroll
        for (int c = 0; c < 64; c += 2) {
            s0 = fmaf(a[c], ip[c * 136], s0);
            s1 = fmaf(a[c + 1], ip[(c + 1) * 136], s1);
        }
        av_s[tid] = s0 + s1;
    }
    __syncthreads();

    // ---- feat[256] = relu(lin_w @ av + lin_b) ----
    if (tid < 256) {
        const float4* wr = reinterpret_cast<const float4*>(lin_w + tid * 680);
        const float4* a4 = reinterpret_cast<const float4*>(av_s);
        float s0 = 0.f, s1 = 0.f;
        #pragma unroll
        for (int q = 0; q < 170; q += 2) {
            float4 a0 = wr[q], c0 = a4[q];
            float4 a1 = wr[q + 1], c1 = a4[q + 1];
            s0 += a0.x * c0.x + a0.y * c0.y + a0.z * c0.z + a0.w * c0.w;
            s1 += a1.x * c1.x + a1.y * c1.y + a1.z * c1.z + a1.w * c1.w;
        }
        feat_s[tid] = fmaxf(s0 + s1 + lin_b[tid], 0.0f);
    }
    __syncthreads();

    // ---- LSTM gates[1024] ----
    {
        const float4* wi = reinterpret_cast<const float4*>(lstm_wih + tid * 256);
        const float4* wh = reinterpret_cast<const float4*>(lstm_whh + tid * 256);
        const float4* f4 = reinterpret_cast<const float4*>(feat_s);
        const float4* x4 = reinterpret_cast<const float4*>(hx_s);
        float s0 = 0.f, s1 = 0.f, s2 = 0.f, s3 = 0.f;
        #pragma unroll
        for (int q = 0; q < 64; q += 2) {
            float4 a0 = wi[q], c0 = f4[q];
            float4 a1 = wi[q + 1], c1 = f4[q + 1];
            float4 b0 = wh[q], d0 = x4[q];
            float4 b1 = wh[q + 1], d1 = x4[q + 1];
            s0 += a0.x * c0.x + a0.y * c0.y + a0.z * c0.z + a0.w * c0.w;
            s1 += a1.x * c1.x + a1.y * c1.y + a1.z * c1.z + a1.w * c1.w;
            s2 += b0.x * d0.x + b0.y * d0.y + b0.z * d0.z + b0.w * d0.w;
            s3 += b1.x * d1.x + b1.y * d1.y + b1.z * d1.z + b1.w * d1.w;
        }
        gates_s[tid] = ((s0 + s1) + (s2 + s3)) + lstm_bih[tid] + lstm_bhh[tid];
    }
    __syncthreads();

    // ---- LSTM cell update + write h2x, c2 ----
    if (tid < 256) {
        float ig = gates_s[tid];
        float fg = gates_s[256 + tid];
        float gg = gates_s[512 + tid];
        float og = gates_s[768 + tid];
        float cc = sigmf(fg) * cx[tid] + sigmf(ig) * tanhf(gg);
        float hh = sigmf(og) * tanhf(cc);
        out[260 + tid] = cc;   // c2
        out[4 + tid] = hh;     // h2x
        f2_s[tid] = hh;
    } else if (tid < 288) {
        f2_s[tid] = time_emb[tx[0] * 32 + (tid - 256)];
    }
    __syncthreads();

    // ---- heads: critic (1 row) + actor (3 rows), one wave each ----
    const int warp = tid >> 6, lane = tid & 63;
    if (warp < 4) {
        const float* wr = (warp == 0) ? critic_w : (actor_w + (warp - 1) * 288);
        float p = 0.0f;
        for (int i = lane; i < 288; i += 64) p = fmaf(f2_s[i], wr[i], p);
        #pragma unroll
        for (int off = 32; off >= 1; off >>= 1) p += __shfl_down(p, off);
        if (lane == 0) {
            float bias = (warp == 0) ? critic_b[0] : actor_b[warp - 1];
            out[warp] = p + bias;   // out[0]=critic, out[1..3]=actor
        }
    }
}

extern "C" void kernel_launch(void* const* d_in, const int* in_sizes, int n_in,
                              void* d_out, int out_size, void* d_ws, size_t ws_size,
                              hipStream_t stream) {
    const float* x        = (const float*)d_in[0];
    const int*   inst     = (const int*)d_in[1];
    const int*   tx       = (const int*)d_in[2];
    const float* hx       = (const float*)d_in[3];
    const float* cx       = (const float*)d_in[4];
    const float* conv1_w  = (const float*)d_in[5];
    const float* conv1_b  = (const float*)d_in[6];
    const float* conv2_w  = (const float*)d_in[7];
    const float* conv2_b  = (const float*)d_in[8];
    const float* conv3_w  = (const float*)d_in[9];
    const float* conv3_b  = (const float*)d_in[10];
    const float* emb      = (const float*)d_in[11];
    const float* gru_wih  = (const float*)d_in[12];
    const float* gru_whh  = (const float*)d_in[13];
    const float* gru_bih  = (const float*)d_in[14];
    const float* gru_bhh  = (const float*)d_in[15];
    const float* attn_w   = (const float*)d_in[16];
    const float* attn_b   = (const float*)d_in[17];
    const float* time_emb = (const float*)d_in[18];
    const float* lin_w    = (const float*)d_in[19];
    const float* lin_b    = (const float*)d_in[20];
    const float* lstm_wih = (const float*)d_in[21];
    const float* lstm_whh = (const float*)d_in[22];
    const float* lstm_bih = (const float*)d_in[23];
    const float* lstm_bhh = (const float*)d_in[24];
    const float* critic_w = (const float*)d_in[25];
    const float* critic_b = (const float*)d_in[26];
    const float* actor_w  = (const float*)d_in[27];
    const float* actor_b  = (const float*)d_in[28];

    float* ws0 = (float*)d_ws;                 // conv1 out: 128*41*74 = 388352
    float* ws1 = ws0 + 388352;                 // conv2 out: 64*19*36  = 43776
    float* ws2 = ws1 + 43776;                  // conv3 out: 64*8*17   = 8704
    float* out = (float*)d_out;                // [516] = critic(1)+actor(3)+h2x(256)+c2(256)

    conv1_k<<<128 * 12, 256, 0, stream>>>(x, conv1_w, conv1_b, ws0);
    conv2_k<<<64 * 3, 256, 0, stream>>>(ws0, conv2_w, conv2_b, ws1);
    conv3_k<<<64, 192, 0, stream>>>(ws1, conv3_w, conv3_b, ws2);
    fused_k<<<1, 1024, 0, stream>>>(inst, tx, hx, cx, emb,
                                    gru_wih, gru_whh, gru_bih, gru_bhh,
                                    attn_w, attn_b, time_emb, lin_w, lin_b,
                                    lstm_wih, lstm_whh, lstm_bih, lstm_bhh,
                                    critic_w, critic_b, actor_w, actor_b,
                                    ws2, out);
}

// Round 5
// 269.707 us; speedup vs baseline: 2.6981x; 2.6981x over previous
//
#include <hip/hip_runtime.h>
#include <math.h>

#define GBLK 12        // coop grid blocks
#define GRU_ROWS 64    // gate rows per block (768/12)
#define WSTR 260       // padded LDS row stride (+4 breaks bank conflicts)

__device__ __forceinline__ float sigmf(float x) { return 1.0f / (1.0f + expf(-x)); }

__device__ __forceinline__ void st_agent(float* p, float v) {
    __hip_atomic_store(p, v, __ATOMIC_RELAXED, __HIP_MEMORY_SCOPE_AGENT);
}

// device-scope barrier: one monotonically-used counter per instance.
// compiler emits s_waitcnt vmcnt(0) before s_barrier -> all stores complete before arrive.
// agent-scope acquire fence after spin invalidates L1 (and volatile L2) before post-barrier reads.
__device__ __forceinline__ void barrier_sync(int* cnt, int target) {
    __syncthreads();
    if (threadIdx.x == 0) {
        __hip_atomic_fetch_add(cnt, 1, __ATOMIC_RELAXED, __HIP_MEMORY_SCOPE_AGENT);
        while (__hip_atomic_load(cnt, __ATOMIC_RELAXED, __HIP_MEMORY_SCOPE_AGENT) < target) {}
    }
    __builtin_amdgcn_fence(__ATOMIC_ACQUIRE, "agent");
    __syncthreads();
}

// ---------------- conv1: x[3,168,300] -> out[128,41,74], k=8, s=4, relu ----------------
__global__ __launch_bounds__(256) void conv1_k(const float* __restrict__ x,
                                               const float* __restrict__ w,
                                               const float* __restrict__ b,
                                               float* __restrict__ out) {
    __shared__ float ws[192];
    const int co = blockIdx.x / 12, chunk = blockIdx.x % 12;
    if (threadIdx.x < 192) ws[threadIdx.x] = w[co * 192 + threadIdx.x];
    __syncthreads();
    const int pix = chunk * 256 + (int)threadIdx.x;
    if (pix >= 41 * 74) return;
    const int oh = pix / 74, ow = pix % 74;
    const float* xp = x + oh * 4 * 300 + ow * 4;   // all float4-aligned offsets
    float acc = b[co];
    #pragma unroll
    for (int ci = 0; ci < 3; ci++) {
        #pragma unroll
        for (int kh = 0; kh < 8; kh++) {
            const float* row = xp + ci * (168 * 300) + kh * 300;
            const float* wr = ws + ci * 64 + kh * 8;
            float4 p0 = *reinterpret_cast<const float4*>(row);
            float4 p1 = *reinterpret_cast<const float4*>(row + 4);
            acc += p0.x * wr[0] + p0.y * wr[1] + p0.z * wr[2] + p0.w * wr[3]
                 + p1.x * wr[4] + p1.y * wr[5] + p1.z * wr[6] + p1.w * wr[7];
        }
    }
    out[co * 3034 + pix] = fmaxf(acc, 0.0f);
}

// ---------------- conv2: in[128,41,74] -> out[64,19,36], k=4, s=2, relu ----------------
__global__ __launch_bounds__(256) void conv2_k(const float* __restrict__ in,
                                               const float* __restrict__ w,
                                               const float* __restrict__ b,
                                               float* __restrict__ out) {
    __shared__ float ws[2048];
    const int co = blockIdx.x / 3, chunk = blockIdx.x % 3;
    for (int i = threadIdx.x; i < 2048; i += 256) ws[i] = w[co * 2048 + i];
    __syncthreads();
    const int pix = chunk * 256 + (int)threadIdx.x;
    if (pix >= 19 * 36) return;
    const int oh = pix / 36, ow = pix % 36;
    const float* base = in + oh * 2 * 74 + ow * 2;   // always even offsets -> float2 ok
    float acc = b[co];
    for (int ci = 0; ci < 128; ci++) {
        const float* ip = base + ci * 3034;
        const float* wc = ws + ci * 16;
        #pragma unroll
        for (int kh = 0; kh < 4; kh++) {
            const float* row = ip + kh * 74;
            const float* wr = wc + kh * 4;
            float2 a0 = *reinterpret_cast<const float2*>(row);
            float2 a1 = *reinterpret_cast<const float2*>(row + 2);
            acc += a0.x * wr[0] + a0.y * wr[1] + a1.x * wr[2] + a1.y * wr[3];
        }
    }
    out[co * 684 + pix] = fmaxf(acc, 0.0f);
}

// ---------------- conv3: in[64,19,36] -> out[64,8,17], k=4, s=2, relu ----------------
__global__ __launch_bounds__(192) void conv3_k(const float* __restrict__ in,
                                               const float* __restrict__ w,
                                               const float* __restrict__ b,
                                               float* __restrict__ out) {
    __shared__ float ws[1024];
    const int co = blockIdx.x;
    for (int i = threadIdx.x; i < 1024; i += 192) ws[i] = w[co * 1024 + i];
    __syncthreads();
    const int pix = threadIdx.x;
    if (pix >= 8 * 17) return;
    const int oh = pix / 17, ow = pix % 17;
    const float* base = in + oh * 2 * 36 + ow * 2;   // even offsets -> float2 ok
    float acc = b[co];
    for (int ci = 0; ci < 64; ci++) {
        const float* ip = base + ci * 684;
        const float* wc = ws + ci * 16;
        #pragma unroll
        for (int kh = 0; kh < 4; kh++) {
            const float* row = ip + kh * 36;
            const float* wr = wc + kh * 4;
            float2 a0 = *reinterpret_cast<const float2*>(row);
            float2 a1 = *reinterpret_cast<const float2*>(row + 2);
            acc += a0.x * wr[0] + a0.y * wr[1] + a1.x * wr[2] + a1.y * wr[3];
        }
    }
    out[co * 136 + pix] = fmaxf(acc, 0.0f);
}

// ------- coop: 12 blocks. GRU (whh slice LDS-resident) + attn + av + lin + LSTM + heads -------
__global__ __launch_bounds__(256) void coop_k(
    const int* __restrict__ inst, const int* __restrict__ tx,
    const float* __restrict__ hx, const float* __restrict__ cx,
    const float* __restrict__ emb,
    const float* __restrict__ wih, const float* __restrict__ whh,
    const float* __restrict__ bih, const float* __restrict__ bhh,
    const float* __restrict__ attn_w, const float* __restrict__ attn_b,
    const float* __restrict__ time_emb,
    const float* __restrict__ lin_w, const float* __restrict__ lin_b,
    const float* __restrict__ lstm_wih, const float* __restrict__ lstm_whh,
    const float* __restrict__ lstm_bih, const float* __restrict__ lstm_bhh,
    const float* __restrict__ critic_w, const float* __restrict__ critic_b,
    const float* __restrict__ actor_w, const float* __restrict__ actor_b,
    const float* __restrict__ img,
    float* __restrict__ gates, float* __restrict__ attn_g, float* __restrict__ av_g,
    float* __restrict__ feat_g, float* __restrict__ lstmg,
    int* __restrict__ cnt, float* __restrict__ out) {

    __shared__ float whh_s[GRU_ROWS * WSTR];   // 65 KB: my 64 whh rows, padded
    __shared__ float gi_s[18 * GRU_ROWS];      // gi (+bih) for all tokens, my rows
    __shared__ float bhh_s[GRU_ROWS];
    __shared__ __align__(16) float h_s[256];
    __shared__ __align__(16) float f2_s[288];

    const int tid = threadIdx.x;
    const int b = blockIdx.x;
    const int rowbase = b * GRU_ROWS;

    // ---- stage whh slice into LDS (coalesced float4) ----
    for (int i = tid; i < GRU_ROWS * 64; i += 256) {
        int r = i >> 6, q = i & 63;
        float4 v = *reinterpret_cast<const float4*>(whh + (rowbase + r) * 256 + q * 4);
        *reinterpret_cast<float4*>(&whh_s[r * WSTR + q * 4]) = v;
    }
    if (tid < GRU_ROWS) bhh_s[tid] = bhh[rowbase + tid];
    h_s[tid] = 0.0f;
    // ---- gi precompute for all 18 tokens (h-independent) ----
    for (int u = tid; u < 18 * GRU_ROWS; u += 256) {
        int t = u >> 6, r = u & 63;
        int tok = inst[t];
        const float4* e4 = reinterpret_cast<const float4*>(emb + tok * 32);
        const float4* w4 = reinterpret_cast<const float4*>(wih + (rowbase + r) * 32);
        float s = 0.f;
        #pragma unroll
        for (int q = 0; q < 8; q++) {
            float4 a = w4[q], c = e4[q];
            s += a.x * c.x + a.y * c.y + a.z * c.z + a.w * c.w;
        }
        gi_s[u] = s + bih[rowbase + r];
    }
    __syncthreads();

    // ---- GRU: 18 steps, 1 device barrier each ----
    const int row = tid >> 2, sub = tid & 3;   // 4 lanes per row
    for (int t = 0; t < 18; t++) {
        const float4* wr4 = reinterpret_cast<const float4*>(&whh_s[row * WSTR + sub * 64]);
        const float4* h4 = reinterpret_cast<const float4*>(&h_s[sub * 64]);
        float s0 = 0.f, s1 = 0.f;
        #pragma unroll
        for (int q = 0; q < 16; q += 2) {
            float4 a0 = wr4[q], c0 = h4[q];
            float4 a1 = wr4[q + 1], c1 = h4[q + 1];
            s0 += a0.x * c0.x + a0.y * c0.y + a0.z * c0.z + a0.w * c0.w;
            s1 += a1.x * c1.x + a1.y * c1.y + a1.z * c1.z + a1.w * c1.w;
        }
        float p = s0 + s1;
        p += __shfl_xor(p, 1);
        p += __shfl_xor(p, 2);
        if (sub == 0) {
            float gh = p + bhh_s[row];
            float gi = gi_s[t * GRU_ROWS + row];
            float* gt = gates + t * 1024;
            if (b < 4)      st_agent(gt + 0 * 256 + rowbase + row, sigmf(gi + gh));        // r
            else if (b < 8) st_agent(gt + 1 * 256 + (rowbase - 256) + row, sigmf(gi + gh)); // z
            else {          st_agent(gt + 2 * 256 + (rowbase - 512) + row, gi);             // ig
                            st_agent(gt + 3 * 256 + (rowbase - 512) + row, gh); }           // hg
        }
        barrier_sync(cnt + t, GBLK);
        // redundant h-update in every block (coalesced plain loads, first-touch post-barrier)
        {
            const float* gt = gates + t * 1024;
            float rr = gt[tid];
            float zz = gt[256 + tid];
            float ig = gt[512 + tid];
            float hg = gt[768 + tid];
            float g = tanhf(ig + rr * hg);
            float hn = (1.f - zz) * g + zz * h_s[tid];
            __syncthreads();
            h_s[tid] = hn;
            __syncthreads();
        }
    }

    // ---- attention rows: blocks 0..9 own 32 rows each ----
    if (b < 10) {
        int ar = b * 32 + (tid >> 3);
        int j = tid & 7;
        const float4* w4 = reinterpret_cast<const float4*>(attn_w + ar * 256 + j * 32);
        const float4* h4 = reinterpret_cast<const float4*>(&h_s[j * 32]);
        float s = 0.f;
        #pragma unroll
        for (int q = 0; q < 8; q++) {
            float4 a = w4[q], c = h4[q];
            s += a.x * c.x + a.y * c.y + a.z * c.z + a.w * c.w;
        }
        s += __shfl_xor(s, 1); s += __shfl_xor(s, 2); s += __shfl_xor(s, 4);
        if (j == 0) st_agent(attn_g + ar, fmaxf(s + attn_b[ar], 0.f));
    }
    barrier_sync(cnt + 18, GBLK);

    // ---- attn_vecs[680]: blocks 0..2 ----
    if (b < 3) {
        int o = b * 256 + tid;
        if (o < 680) {
            int k = o / 136, rem = o - k * 136;
            const float* ag = attn_g + k * 64;
            const float* ip = img + rem;
            float s = 0.f;
            #pragma unroll 8
            for (int c = 0; c < 64; c++) s = fmaf(ag[c], ip[c * 136], s);
            st_agent(av_g + o, s);
        }
    }
    barrier_sync(cnt + 19, GBLK);

    // ---- feat[256] = relu(lin_w @ av + b): blocks 0..7, wave per 8 rows ----
    if (b < 8) {
        int wv = tid >> 6, lane = tid & 63;
        for (int rr = 0; rr < 8; rr++) {
            int lr = b * 32 + wv * 8 + rr;
            const float4* w4 = reinterpret_cast<const float4*>(lin_w + lr * 680);
            const float4* a4 = reinterpret_cast<const float4*>(av_g);
            float s = 0.f;
            for (int i = lane; i < 170; i += 64) {
                float4 a = w4[i], c = a4[i];
                s += a.x * c.x + a.y * c.y + a.z * c.z + a.w * c.w;
            }
            #pragma unroll
            for (int off = 32; off >= 1; off >>= 1) s += __shfl_down(s, off);
            if (lane == 0) st_agent(feat_g + lr, fmaxf(s + lin_b[lr], 0.f));
        }
    }
    barrier_sync(cnt + 20, GBLK);

    // ---- LSTM gates[1024]: 48 waves × ~22 rows, row per wave-pass ----
    {
        int lane = tid & 63;
        int gw = b * 4 + (tid >> 6);
        int r0 = gw * 22, r1 = min(1024, r0 + 22);
        const float4* f4 = reinterpret_cast<const float4*>(feat_g);
        const float4* x4 = reinterpret_cast<const float4*>(hx);
        for (int r = r0; r < r1; r++) {
            const float4* wi4 = reinterpret_cast<const float4*>(lstm_wih + r * 256);
            const float4* wh4 = reinterpret_cast<const float4*>(lstm_whh + r * 256);
            float4 a = wi4[lane], c = f4[lane];
            float s = a.x * c.x + a.y * c.y + a.z * c.z + a.w * c.w;
            float4 d = wh4[lane], e = x4[lane];
            s += d.x * e.x + d.y * e.y + d.z * e.z + d.w * e.w;
            #pragma unroll
            for (int off = 32; off >= 1; off >>= 1) s += __shfl_down(s, off);
            if (lane == 0) st_agent(lstmg + r, s + lstm_bih[r] + lstm_bhh[r]);
        }
    }
    barrier_sync(cnt + 21, GBLK);

    // ---- cell update + heads: block 0 only ----
    if (b == 0) {
        float ig = lstmg[tid], fg = lstmg[256 + tid], gg = lstmg[512 + tid], og = lstmg[768 + tid];
        float cc = sigmf(fg) * cx[tid] + sigmf(ig) * tanhf(gg);
        float hh = sigmf(og) * tanhf(cc);
        out[260 + tid] = cc;   // c2
        out[4 + tid] = hh;     // h2x
        f2_s[tid] = hh;
        if (tid < 32) f2_s[256 + tid] = time_emb[tx[0] * 32 + tid];
        __syncthreads();
        int wv = tid >> 6, lane = tid & 63;
        const float* wr = (wv == 0) ? critic_w : (actor_w + (wv - 1) * 288);
        float p = 0.f;
        for (int i = lane; i < 288; i += 64) p = fmaf(f2_s[i], wr[i], p);
        #pragma unroll
        for (int off = 32; off >= 1; off >>= 1) p += __shfl_down(p, off);
        if (lane == 0) out[wv] = p + ((wv == 0) ? critic_b[0] : actor_b[wv - 1]);
    }
}

extern "C" void kernel_launch(void* const* d_in, const int* in_sizes, int n_in,
                              void* d_out, int out_size, void* d_ws, size_t ws_size,
                              hipStream_t stream) {
    const float* x        = (const float*)d_in[0];
    const int*   inst     = (const int*)d_in[1];
    const int*   tx       = (const int*)d_in[2];
    const float* hx       = (const float*)d_in[3];
    const float* cx       = (const float*)d_in[4];
    const float* conv1_w  = (const float*)d_in[5];
    const float* conv1_b  = (const float*)d_in[6];
    const float* conv2_w  = (const float*)d_in[7];
    const float* conv2_b  = (const float*)d_in[8];
    const float* conv3_w  = (const float*)d_in[9];
    const float* conv3_b  = (const float*)d_in[10];
    const float* emb      = (const float*)d_in[11];
    const float* gru_wih  = (const float*)d_in[12];
    const float* gru_whh  = (const float*)d_in[13];
    const float* gru_bih  = (const float*)d_in[14];
    const float* gru_bhh  = (const float*)d_in[15];
    const float* attn_w   = (const float*)d_in[16];
    const float* attn_b   = (const float*)d_in[17];
    const float* time_emb = (const float*)d_in[18];
    const float* lin_w    = (const float*)d_in[19];
    const float* lin_b    = (const float*)d_in[20];
    const float* lstm_wih = (const float*)d_in[21];
    const float* lstm_whh = (const float*)d_in[22];
    const float* lstm_bih = (const float*)d_in[23];
    const float* lstm_bhh = (const float*)d_in[24];
    const float* critic_w = (const float*)d_in[25];
    const float* critic_b = (const float*)d_in[26];
    const float* actor_w  = (const float*)d_in[27];
    const float* actor_b  = (const float*)d_in[28];

    float* wsf = (float*)d_ws;
    // conv buffers
    float* c1o = wsf;                    // [128*41*74 = 388352]
    float* c2o = wsf + 388352;           // [64*19*36  = 43776]
    float* img = wsf + 432128;           // [64*8*17   = 8704]
    // comm buffers OVERLAY conv1-out (conv1-out dead once conv2 finishes; coop runs after)
    float* gates  = wsf;                 // [18*4*256 = 18432]
    float* attn_g = wsf + 18432;         // [320]
    float* av_g   = wsf + 18752;         // [680]
    float* feat_g = wsf + 19432;         // [256]
    float* lstmg  = wsf + 19688;         // [1024]
    int*   cnt    = (int*)(wsf + 440832); // [22] barrier counters (outside conv buffers)
    float* out    = (float*)d_out;       // [516] = critic(1)+actor(3)+h2x(256)+c2(256)

    hipMemsetAsync(cnt, 0, 22 * sizeof(int), stream);   // re-zero barriers every replay
    conv1_k<<<128 * 12, 256, 0, stream>>>(x, conv1_w, conv1_b, c1o);
    conv2_k<<<64 * 3, 256, 0, stream>>>(c1o, conv2_w, conv2_b, c2o);
    conv3_k<<<64, 192, 0, stream>>>(c2o, conv3_w, conv3_b, img);
    coop_k<<<GBLK, 256, 0, stream>>>(inst, tx, hx, cx, emb,
                                     gru_wih, gru_whh, gru_bih, gru_bhh,
                                     attn_w, attn_b, time_emb, lin_w, lin_b,
                                     lstm_wih, lstm_whh, lstm_bih, lstm_bhh,
                                     critic_w, critic_b, actor_w, actor_b,
                                     img, gates, attn_g, av_g, feat_g, lstmg,
                                     cnt, out);
}

// Round 6
// 254.985 us; speedup vs baseline: 2.8538x; 1.0577x over previous
//
#include <hip/hip_runtime.h>
#include <math.h>

#define MAGIC 0x3C96A5F1
#define NGRU 8
#define NWRK 88
#define NBLK (NGRU + NWRK)   // 96 blocks <= 256 CUs -> co-resident
#define NFLAGS 464           // gf144 attf8 featf8 c1f88 c2f88 imgf64 lstmf64

__device__ __forceinline__ float sigmf(float x) { return 1.0f / (1.0f + expf(-x)); }

__device__ __forceinline__ void st_agent(float* p, float v) {
    __hip_atomic_store(p, v, __ATOMIC_RELAXED, __HIP_MEMORY_SCOPE_AGENT);
}
// flag set: preceding __syncthreads() guarantees all block stores drained (vmcnt(0))
__device__ __forceinline__ void st_flag(int* p) {
    __hip_atomic_store(p, MAGIC, __ATOMIC_RELEASE, __HIP_MEMORY_SCOPE_AGENT);
}
// poll n flags (one per thread), then acquire-fence + block barrier.
// data written before those flags is read only AFTER this returns (first-touch).
__device__ __forceinline__ void poll_flags(const int* f, int n, int tid) {
    if (tid < n) {
        while (__hip_atomic_load(f + tid, __ATOMIC_RELAXED, __HIP_MEMORY_SCOPE_AGENT) != MAGIC) {}
    }
    __builtin_amdgcn_fence(__ATOMIC_ACQUIRE, "agent");
    __syncthreads();
}

__global__ __launch_bounds__(256) void mega_k(
    const float* __restrict__ x, const int* __restrict__ inst, const int* __restrict__ tx,
    const float* __restrict__ hx, const float* __restrict__ cx,
    const float* __restrict__ conv1_w, const float* __restrict__ conv1_b,
    const float* __restrict__ conv2_w, const float* __restrict__ conv2_b,
    const float* __restrict__ conv3_w, const float* __restrict__ conv3_b,
    const float* __restrict__ emb,
    const float* __restrict__ wih, const float* __restrict__ whh,
    const float* __restrict__ bih, const float* __restrict__ bhh,
    const float* __restrict__ attn_w, const float* __restrict__ attn_b,
    const float* __restrict__ time_emb,
    const float* __restrict__ lin_w, const float* __restrict__ lin_b,
    const float* __restrict__ lstm_wih, const float* __restrict__ lstm_whh,
    const float* __restrict__ lstm_bih, const float* __restrict__ lstm_bhh,
    const float* __restrict__ critic_w, const float* __restrict__ critic_b,
    const float* __restrict__ actor_w, const float* __restrict__ actor_b,
    float* __restrict__ c1o, float* __restrict__ c2o, float* __restrict__ img,
    float* __restrict__ hglob, float* __restrict__ attn_g, float* __restrict__ feat_g,
    float* __restrict__ lstmg, int* __restrict__ flags,
    float* __restrict__ out) {

    // flag region layout (contiguous for end-clear)
    int* gf    = flags;          // [18*8]
    int* attf  = flags + 144;    // [8]
    int* featf = flags + 152;    // [8]
    int* c1f   = flags + 160;    // [88]
    int* c2f   = flags + 248;    // [88]
    int* imgf  = flags + 336;    // [64]
    int* lstmf = flags + 400;    // [64]

    __shared__ float ws[2048];          // conv weight staging (worker path)
    __shared__ float gi_s[18 * 96];     // gi(+bih) for all tokens, this block's 96 rows
    __shared__ float wt_all[18 * 32];   // token embeddings
    __shared__ float bhh_s[96];
    __shared__ __align__(16) float h_s[256];
    __shared__ __align__(16) float attn_s[320];
    __shared__ __align__(16) float av_s[680];
    __shared__ __align__(16) float f2_s[288];

    const int tid = threadIdx.x;
    const int b = blockIdx.x;

    if (b < NGRU) {
        // ================= GRU path: block owns h-dims [b*32, b*32+32) =================
        const int d = tid >> 3;          // 0..31 dim within slice
        const int ch = tid & 7;          // 8 col-chunks of 32
        const int dimg = b * 32 + d;     // global h dim

        // whh rows (r,z,g gates of dim) resident in registers: 3 x 8 float4
        float4 wr_[8], wz_[8], wg_[8];
        {
            const float4* p0 = reinterpret_cast<const float4*>(whh + (0 * 256 + dimg) * 256 + ch * 32);
            const float4* p1 = reinterpret_cast<const float4*>(whh + (1 * 256 + dimg) * 256 + ch * 32);
            const float4* p2 = reinterpret_cast<const float4*>(whh + (2 * 256 + dimg) * 256 + ch * 32);
            #pragma unroll
            for (int j = 0; j < 8; j++) { wr_[j] = p0[j]; wz_[j] = p1[j]; wg_[j] = p2[j]; }
        }
        for (int i = tid; i < 18 * 32; i += 256) wt_all[i] = emb[inst[i >> 5] * 32 + (i & 31)];
        if (tid < 96) bhh_s[tid] = bhh[(tid >> 5) * 256 + b * 32 + (tid & 31)];
        h_s[tid] = 0.0f;
        __syncthreads();

        // gi precompute (h-independent): gi_s[t*96 + gate*32 + j]
        for (int u = tid; u < 18 * 96; u += 256) {
            int t = u / 96, r = u % 96;
            int R = (r >> 5) * 256 + b * 32 + (r & 31);
            const float4* w4 = reinterpret_cast<const float4*>(wih + R * 32);
            const float4* e4 = reinterpret_cast<const float4*>(wt_all + t * 32);
            float s = 0.f;
            #pragma unroll
            for (int q = 0; q < 8; q++) {
                float4 a = w4[q], c = e4[q];
                s += a.x * c.x + a.y * c.y + a.z * c.z + a.w * c.w;
            }
            gi_s[u] = s + bih[R];
        }
        __syncthreads();

        // ---- 18 GRU steps, one flag-exchange each ----
        for (int t = 0; t < 18; t++) {
            const float4* h4 = reinterpret_cast<const float4*>(h_s + ch * 32);
            float p0 = 0.f, p1 = 0.f, p2 = 0.f;
            #pragma unroll
            for (int j = 0; j < 8; j++) {
                float4 c = h4[j];
                p0 += wr_[j].x * c.x + wr_[j].y * c.y + wr_[j].z * c.z + wr_[j].w * c.w;
                p1 += wz_[j].x * c.x + wz_[j].y * c.y + wz_[j].z * c.z + wz_[j].w * c.w;
                p2 += wg_[j].x * c.x + wg_[j].y * c.y + wg_[j].z * c.z + wg_[j].w * c.w;
            }
            p0 += __shfl_xor(p0, 1); p0 += __shfl_xor(p0, 2); p0 += __shfl_xor(p0, 4);
            p1 += __shfl_xor(p1, 1); p1 += __shfl_xor(p1, 2); p1 += __shfl_xor(p1, 4);
            p2 += __shfl_xor(p2, 1); p2 += __shfl_xor(p2, 2); p2 += __shfl_xor(p2, 4);
            if (ch == 0) {
                float ghr = p0 + bhh_s[d];
                float ghz = p1 + bhh_s[32 + d];
                float ghg = p2 + bhh_s[64 + d];
                float ir = gi_s[t * 96 + d], iz = gi_s[t * 96 + 32 + d], ig = gi_s[t * 96 + 64 + d];
                float rr = sigmf(ir + ghr);
                float zz = sigmf(iz + ghz);
                float gg = tanhf(ig + rr * ghg);
                float hn = (1.f - zz) * gg + zz * h_s[dimg];
                st_agent(hglob + t * 256 + dimg, hn);
            }
            __syncthreads();                       // drain stores (vmcnt 0) before flag
            if (tid == 0) st_flag(gf + t * 8 + b);
            poll_flags(gf + t * 8, 8, tid);        // fence + barrier inside
            h_s[tid] = hglob[t * 256 + tid];       // first touch post-flags
            __syncthreads();
        }

        // ---- attention rows [b*40, b*40+40): 4 threads/row ----
        {
            int lr = tid >> 2, ln = tid & 3;
            if (lr < 40) {
                int a = b * 40 + lr;
                const float4* w4 = reinterpret_cast<const float4*>(attn_w + a * 256 + ln * 64);
                const float4* h4 = reinterpret_cast<const float4*>(h_s + ln * 64);
                float s = 0.f;
                #pragma unroll
                for (int q = 0; q < 16; q++) {
                    float4 aa = w4[q], cc = h4[q];
                    s += aa.x * cc.x + aa.y * cc.y + aa.z * cc.z + aa.w * cc.w;
                }
                s += __shfl_xor(s, 1); s += __shfl_xor(s, 2);
                if (ln == 0) st_agent(attn_g + a, fmaxf(s + attn_b[a], 0.f));
            }
            __syncthreads();
            if (tid == 0) st_flag(attf + b);
        }

        // ---- wait attn(8) + img(64), then redundant av + own feat rows ----
        if (tid < 8) {
            while (__hip_atomic_load(attf + tid, __ATOMIC_RELAXED, __HIP_MEMORY_SCOPE_AGENT) != MAGIC) {}
        } else if (tid < 72) {
            while (__hip_atomic_load(imgf + tid - 8, __ATOMIC_RELAXED, __HIP_MEMORY_SCOPE_AGENT) != MAGIC) {}
        }
        __builtin_amdgcn_fence(__ATOMIC_ACQUIRE, "agent");
        __syncthreads();

        for (int i = tid; i < 320; i += 256) attn_s[i] = attn_g[i];
        __syncthreads();
        for (int o = tid; o < 680; o += 256) {
            int k = o / 136, rem = o - k * 136;
            const float* ag = attn_s + k * 64;
            const float* ip = img + rem;
            float s = 0.f;
            #pragma unroll 8
            for (int c = 0; c < 64; c++) s = fmaf(ag[c], ip[c * 136], s);
            av_s[o] = s;
        }
        __syncthreads();
        {   // feat rows [b*32, +32): 8 threads/row
            int lr = tid >> 3, ln = tid & 7;
            int fr = b * 32 + lr;
            const float4* w4 = reinterpret_cast<const float4*>(lin_w + fr * 680);
            const float4* a4 = reinterpret_cast<const float4*>(av_s);
            float s = 0.f;
            for (int c = ln; c < 170; c += 8) {
                float4 a = w4[c], cc = a4[c];
                s += a.x * cc.x + a.y * cc.y + a.z * cc.z + a.w * cc.w;
            }
            s += __shfl_xor(s, 1); s += __shfl_xor(s, 2); s += __shfl_xor(s, 4);
            if (ln == 0) st_agent(feat_g + fr, fmaxf(s + lin_b[fr], 0.f));
            __syncthreads();
            if (tid == 0) st_flag(featf + b);
        }

        // ---- block 0: LSTM cell + heads + flag self-clean ----
        if (b == 0) {
            poll_flags(lstmf, 64, tid);
            float ig = lstmg[tid], fg = lstmg[256 + tid], gg = lstmg[512 + tid], og = lstmg[768 + tid];
            float cc = sigmf(fg) * cx[tid] + sigmf(ig) * tanhf(gg);
            float hh = sigmf(og) * tanhf(cc);
            out[260 + tid] = cc;   // c2
            out[4 + tid] = hh;     // h2x
            f2_s[tid] = hh;
            if (tid < 32) f2_s[256 + tid] = time_emb[tx[0] * 32 + tid];
            __syncthreads();
            int wv = tid >> 6, ln = tid & 63;
            const float* wr = (wv == 0) ? critic_w : (actor_w + (wv - 1) * 288);
            float p = 0.f;
            for (int i = ln; i < 288; i += 64) p = fmaf(f2_s[i], wr[i], p);
            #pragma unroll
            for (int off = 32; off >= 1; off >>= 1) p += __shfl_down(p, off);
            if (ln == 0) out[wv] = p + ((wv == 0) ? critic_b[0] : actor_b[wv - 1]);
            // self-clean flags: every flag transitively precedes lstmf, and all
            // pollers have passed their last poll once lstmf is fully set.
            __syncthreads();
            for (int i = tid; i < NFLAGS; i += 256) flags[i] = 0;
        }
    } else {
        // ================= worker path: convs then LSTM gate rows =================
        const int wb = b - NGRU;   // 0..87

        // ---- conv1: 1536 tiles of (co, 256px-chunk) ----
        for (int tile = wb; tile < 1536; tile += NWRK) {
            int co = tile / 12, chunk = tile % 12;
            __syncthreads();
            if (tid < 192) ws[tid] = conv1_w[co * 192 + tid];
            __syncthreads();
            int pix = chunk * 256 + tid;
            if (pix < 3034) {
                int oh = pix / 74, ow = pix % 74;
                const float* xp = x + oh * 4 * 300 + ow * 4;
                float acc = conv1_b[co];
                #pragma unroll
                for (int ci = 0; ci < 3; ci++) {
                    #pragma unroll
                    for (int kh = 0; kh < 8; kh++) {
                        const float* row = xp + ci * (168 * 300) + kh * 300;
                        const float* wr = ws + ci * 64 + kh * 8;
                        float4 q0 = *reinterpret_cast<const float4*>(row);
                        float4 q1 = *reinterpret_cast<const float4*>(row + 4);
                        acc += q0.x * wr[0] + q0.y * wr[1] + q0.z * wr[2] + q0.w * wr[3]
                             + q1.x * wr[4] + q1.y * wr[5] + q1.z * wr[6] + q1.w * wr[7];
                    }
                }
                st_agent(c1o + co * 3034 + pix, fmaxf(acc, 0.f));
            }
        }
        __syncthreads();
        if (tid == 0) st_flag(c1f + wb);
        poll_flags(c1f, NWRK, tid);

        // ---- conv2: 192 tiles of (co, 256px-chunk) ----
        for (int tile = wb; tile < 192; tile += NWRK) {
            int co = tile / 3, chunk = tile % 3;
            __syncthreads();
            for (int i = tid; i < 2048; i += 256) ws[i] = conv2_w[co * 2048 + i];
            __syncthreads();
            int pix = chunk * 256 + tid;
            if (pix < 684) {
                int oh = pix / 36, ow = pix % 36;
                const float* base = c1o + oh * 2 * 74 + ow * 2;
                float acc = conv2_b[co];
                for (int ci = 0; ci < 128; ci++) {
                    const float* ip = base + ci * 3034;
                    const float* wc = ws + ci * 16;
                    #pragma unroll
                    for (int kh = 0; kh < 4; kh++) {
                        const float* row = ip + kh * 74;
                        const float* wr = wc + kh * 4;
                        float2 a0 = *reinterpret_cast<const float2*>(row);
                        float2 a1 = *reinterpret_cast<const float2*>(row + 2);
                        acc += a0.x * wr[0] + a0.y * wr[1] + a1.x * wr[2] + a1.y * wr[3];
                    }
                }
                st_agent(c2o + co * 684 + pix, fmaxf(acc, 0.f));
            }
        }
        __syncthreads();
        if (tid == 0) st_flag(c2f + wb);

        if (wb < 64) {
            poll_flags(c2f, NWRK, tid);
            // ---- conv3: tile wb = one co ----
            {
                int co = wb;
                for (int i = tid; i < 1024; i += 256) ws[i] = conv3_w[co * 1024 + i];
                __syncthreads();
                if (tid < 136) {
                    int oh = tid / 17, ow = tid % 17;
                    const float* base = c2o + oh * 2 * 36 + ow * 2;
                    float acc = conv3_b[co];
                    for (int ci = 0; ci < 64; ci++) {
                        const float* ip = base + ci * 684;
                        const float* wc = ws + ci * 16;
                        #pragma unroll
                        for (int kh = 0; kh < 4; kh++) {
                            const float* row = ip + kh * 36;
                            const float* wr = wc + kh * 4;
                            float2 a0 = *reinterpret_cast<const float2*>(row);
                            float2 a1 = *reinterpret_cast<const float2*>(row + 2);
                            acc += a0.x * wr[0] + a0.y * wr[1] + a1.x * wr[2] + a1.y * wr[3];
                        }
                    }
                    st_agent(img + co * 136 + tid, fmaxf(acc, 0.f));
                }
                __syncthreads();
                if (tid == 0) st_flag(imgf + wb);
            }
            // ---- LSTM gate rows [wb*16, +16): 16 threads/row, wih@feat + whh@hx ----
            poll_flags(featf, 8, tid);
            {
                int lr = tid >> 4, ln = tid & 15;
                int r = wb * 16 + lr;
                const float4* wi4 = reinterpret_cast<const float4*>(lstm_wih + r * 256);
                const float4* wh4 = reinterpret_cast<const float4*>(lstm_whh + r * 256);
                const float4* f4 = reinterpret_cast<const float4*>(feat_g);
                const float4* x4 = reinterpret_cast<const float4*>(hx);
                float s = 0.f;
                #pragma unroll
                for (int q = 0; q < 4; q++) {
                    float4 a = wi4[ln * 4 + q], c = f4[ln * 4 + q];
                    s += a.x * c.x + a.y * c.y + a.z * c.z + a.w * c.w;
                    float4 dd = wh4[ln * 4 + q], e = x4[ln * 4 + q];
                    s += dd.x * e.x + dd.y * e.y + dd.z * e.z + dd.w * e.w;
                }
                s += __shfl_xor(s, 1); s += __shfl_xor(s, 2);
                s += __shfl_xor(s, 4); s += __shfl_xor(s, 8);
                if (ln == 0) st_agent(lstmg + r, s + lstm_bih[r] + lstm_bhh[r]);
                __syncthreads();
                if (tid == 0) st_flag(lstmf + wb);
            }
        }
    }
}

extern "C" void kernel_launch(void* const* d_in, const int* in_sizes, int n_in,
                              void* d_out, int out_size, void* d_ws, size_t ws_size,
                              hipStream_t stream) {
    const float* x        = (const float*)d_in[0];
    const int*   inst     = (const int*)d_in[1];
    const int*   tx       = (const int*)d_in[2];
    const float* hx       = (const float*)d_in[3];
    const float* cx       = (const float*)d_in[4];
    const float* conv1_w  = (const float*)d_in[5];
    const float* conv1_b  = (const float*)d_in[6];
    const float* conv2_w  = (const float*)d_in[7];
    const float* conv2_b  = (const float*)d_in[8];
    const float* conv3_w  = (const float*)d_in[9];
    const float* conv3_b  = (const float*)d_in[10];
    const float* emb      = (const float*)d_in[11];
    const float* gru_wih  = (const float*)d_in[12];
    const float* gru_whh  = (const float*)d_in[13];
    const float* gru_bih  = (const float*)d_in[14];
    const float* gru_bhh  = (const float*)d_in[15];
    const float* attn_w   = (const float*)d_in[16];
    const float* attn_b   = (const float*)d_in[17];
    const float* time_emb = (const float*)d_in[18];
    const float* lin_w    = (const float*)d_in[19];
    const float* lin_b    = (const float*)d_in[20];
    const float* lstm_wih = (const float*)d_in[21];
    const float* lstm_whh = (const float*)d_in[22];
    const float* lstm_bih = (const float*)d_in[23];
    const float* lstm_bhh = (const float*)d_in[24];
    const float* critic_w = (const float*)d_in[25];
    const float* critic_b = (const float*)d_in[26];
    const float* actor_w  = (const float*)d_in[27];
    const float* actor_b  = (const float*)d_in[28];

    float* wsf = (float*)d_ws;
    float* c1o    = wsf;                  // [388352]
    float* c2o    = wsf + 388352;         // [43776]
    float* img    = wsf + 432128;         // [8704]
    float* hglob  = wsf + 440832;         // [18*256 = 4608]
    float* attn_g = wsf + 445440;         // [320]
    float* feat_g = wsf + 445760;         // [256]
    float* lstmg  = wsf + 446016;         // [1024]
    int*   flags  = (int*)(wsf + 447040); // [464] ints; poison(0xAA) != MAGIC, self-cleaned
    float* out    = (float*)d_out;        // [516] = critic(1)+actor(3)+h2x(256)+c2(256)

    mega_k<<<NBLK, 256, 0, stream>>>(x, inst, tx, hx, cx,
                                     conv1_w, conv1_b, conv2_w, conv2_b, conv3_w, conv3_b,
                                     emb, gru_wih, gru_whh, gru_bih, gru_bhh,
                                     attn_w, attn_b, time_emb, lin_w, lin_b,
                                     lstm_wih, lstm_whh, lstm_bih, lstm_bhh,
                                     critic_w, critic_b, actor_w, actor_b,
                                     c1o, c2o, img, hglob, attn_g, feat_g, lstmg,
                                     flags, out);
}

// Round 7
// 206.394 us; speedup vs baseline: 3.5257x; 1.2354x over previous
//
#include <hip/hip_runtime.h>
#include <math.h>

#define MAGIC 0x3C96A5F1
#define NGRU 8
#define NWRK 240
#define NBLK (NGRU + NWRK)   // 248 blocks, 122KB LDS -> 1 block/CU, all co-resident
#define WSTR 260             // whh LDS row stride (floats): 8 rows spread over banks
#define ATAG 7u
#define FTAG 9u
#define LTAG 11u

__device__ __forceinline__ float sigmf(float x) { return 1.0f / (1.0f + expf(-x)); }

__device__ __forceinline__ void st_agent(float* p, float v) {
    __hip_atomic_store(p, v, __ATOMIC_RELAXED, __HIP_MEMORY_SCOPE_AGENT);
}
__device__ __forceinline__ void st_flag(int* p) {
    __hip_atomic_store(p, MAGIC, __ATOMIC_RELEASE, __HIP_MEMORY_SCOPE_AGENT);
}
__device__ __forceinline__ void poll_flags(const int* f, int n, int tid) {
    if (tid < n) {
        while (__hip_atomic_load(f + tid, __ATOMIC_RELAXED, __HIP_MEMORY_SCOPE_AGENT) != MAGIC) {}
    }
    __builtin_amdgcn_fence(__ATOMIC_ACQUIRE, "agent");
    __syncthreads();
}
// single-word publish: (tag<<32)|bits — value rides with the tag, no fence needed
__device__ __forceinline__ void st_pk(unsigned long long* p, unsigned tag, float v) {
    __hip_atomic_store(p, ((unsigned long long)tag << 32) | (unsigned long long)__float_as_uint(v),
                       __ATOMIC_RELAXED, __HIP_MEMORY_SCOPE_AGENT);
}
__device__ __forceinline__ float poll_pk(const unsigned long long* p, unsigned tag) {
    unsigned long long v;
    do { v = __hip_atomic_load(p, __ATOMIC_RELAXED, __HIP_MEMORY_SCOPE_AGENT); }
    while ((unsigned)(v >> 32) != tag);
    return __uint_as_float((unsigned)(v & 0xffffffffu));
}

__global__ __launch_bounds__(256) void mega_k(
    const float* __restrict__ x, const int* __restrict__ inst, const int* __restrict__ tx,
    const float* __restrict__ hx, const float* __restrict__ cx,
    const float* __restrict__ conv1_w, const float* __restrict__ conv1_b,
    const float* __restrict__ conv2_w, const float* __restrict__ conv2_b,
    const float* __restrict__ conv3_w, const float* __restrict__ conv3_b,
    const float* __restrict__ emb,
    const float* __restrict__ wih, const float* __restrict__ whh,
    const float* __restrict__ bih, const float* __restrict__ bhh,
    const float* __restrict__ attn_w, const float* __restrict__ attn_b,
    const float* __restrict__ time_emb,
    const float* __restrict__ lin_w, const float* __restrict__ lin_b,
    const float* __restrict__ lstm_wih, const float* __restrict__ lstm_whh,
    const float* __restrict__ lstm_bih, const float* __restrict__ lstm_bhh,
    const float* __restrict__ critic_w, const float* __restrict__ critic_b,
    const float* __restrict__ actor_w, const float* __restrict__ actor_b,
    float* __restrict__ c1o, float* __restrict__ c2o, float* __restrict__ img,
    unsigned long long* __restrict__ hpk,   // [18*256] (tag t+1, value h_t[dim])
    unsigned long long* __restrict__ apk,   // [320]
    unsigned long long* __restrict__ fpk,   // [256]
    unsigned long long* __restrict__ lpk,   // [1024]
    int* __restrict__ flags,                // c1f[240] c2f[240] imgf[64]
    float* __restrict__ out) {

    int* c1f  = flags;
    int* c2f  = flags + 240;
    int* imgf = flags + 480;

    __shared__ float whh_s[96 * WSTR];      // 97.5 KB: this block's 96 whh rows
    __shared__ float gi_s[18 * 96];
    __shared__ float wt_all[18 * 32];
    __shared__ float bhh_s[96];
    __shared__ __align__(16) float h_s[256];
    __shared__ __align__(16) float attn_s[320];
    __shared__ __align__(16) float av_s[680];
    __shared__ __align__(16) float f2_s[288];
    __shared__ __align__(16) float ws[2048];      // conv weight staging (workers)
    __shared__ __align__(16) float feat_ls[256];  // feat staged (workers)

    const int tid = threadIdx.x;
    const int b = blockIdx.x;

    if (b < NGRU) {
        // ============== GRU path: block owns h-dims [b*32, b*32+32) ==============
        const int d = tid >> 3;          // dim within slice
        const int ch = tid & 7;          // 8 col-chunks of 32
        const int dimg = b * 32 + d;

        // stage whh rows (r,z,g of my dims) into LDS, coalesced float4
        for (int i = tid; i < 96 * 64; i += 256) {
            int lr = i >> 6, q = i & 63;
            int gr = (lr >> 5) * 256 + b * 32 + (lr & 31);
            float4 v = *reinterpret_cast<const float4*>(whh + gr * 256 + q * 4);
            *reinterpret_cast<float4*>(&whh_s[lr * WSTR + q * 4]) = v;
        }
        for (int i = tid; i < 18 * 32; i += 256) wt_all[i] = emb[inst[i >> 5] * 32 + (i & 31)];
        if (tid < 96) bhh_s[tid] = bhh[(tid >> 5) * 256 + b * 32 + (tid & 31)];
        h_s[tid] = 0.0f;
        __syncthreads();

        // gi precompute (h-independent): gi_s[t*96 + gate*32 + j]
        for (int u = tid; u < 18 * 96; u += 256) {
            int t = u / 96, r = u % 96;
            int R = (r >> 5) * 256 + b * 32 + (r & 31);
            const float4* w4 = reinterpret_cast<const float4*>(wih + R * 32);
            const float4* e4 = reinterpret_cast<const float4*>(wt_all + t * 32);
            float s = 0.f;
            #pragma unroll
            for (int q = 0; q < 8; q++) {
                float4 a = w4[q], c = e4[q];
                s += a.x * c.x + a.y * c.y + a.z * c.z + a.w * c.w;
            }
            gi_s[u] = s + bih[R];
        }
        __syncthreads();

        // ---- 18 GRU steps: one packet RTT each ----
        for (int t = 0; t < 18; t++) {
            const float4* hr4 = reinterpret_cast<const float4*>(h_s + ch * 32);
            const float4* w0 = reinterpret_cast<const float4*>(&whh_s[d * WSTR + ch * 32]);
            const float4* w1 = reinterpret_cast<const float4*>(&whh_s[(32 + d) * WSTR + ch * 32]);
            const float4* w2 = reinterpret_cast<const float4*>(&whh_s[(64 + d) * WSTR + ch * 32]);
            float p0 = 0.f, p1 = 0.f, p2 = 0.f;
            #pragma unroll
            for (int j = 0; j < 8; j++) {
                float4 c = hr4[j];
                float4 a0 = w0[j], a1 = w1[j], a2 = w2[j];
                p0 += a0.x * c.x + a0.y * c.y + a0.z * c.z + a0.w * c.w;
                p1 += a1.x * c.x + a1.y * c.y + a1.z * c.z + a1.w * c.w;
                p2 += a2.x * c.x + a2.y * c.y + a2.z * c.z + a2.w * c.w;
            }
            p0 += __shfl_xor(p0, 1); p0 += __shfl_xor(p0, 2); p0 += __shfl_xor(p0, 4);
            p1 += __shfl_xor(p1, 1); p1 += __shfl_xor(p1, 2); p1 += __shfl_xor(p1, 4);
            p2 += __shfl_xor(p2, 1); p2 += __shfl_xor(p2, 2); p2 += __shfl_xor(p2, 4);
            if (ch == 0) {
                float ghr = p0 + bhh_s[d];
                float ghz = p1 + bhh_s[32 + d];
                float ghg = p2 + bhh_s[64 + d];
                float rr = sigmf(gi_s[t * 96 + d] + ghr);
                float zz = sigmf(gi_s[t * 96 + 32 + d] + ghz);
                float gg = tanhf(gi_s[t * 96 + 64 + d] + rr * ghg);
                float hn = (1.f - zz) * gg + zz * h_s[dimg];
                st_pk(hpk + t * 256 + dimg, (unsigned)(t + 1), hn);
            }
            float hv = poll_pk(hpk + t * 256 + tid, (unsigned)(t + 1));
            __syncthreads();          // everyone done computing/polling before h_s overwrite
            h_s[tid] = hv;
            __syncthreads();
        }

        // ---- attention rows [b*40, b*40+40): 4 threads/row ----
        {
            int lr = tid >> 2, ln = tid & 3;
            if (lr < 40) {
                int a = b * 40 + lr;
                const float4* w4 = reinterpret_cast<const float4*>(attn_w + a * 256 + ln * 64);
                const float4* h4 = reinterpret_cast<const float4*>(h_s + ln * 64);
                float s = 0.f;
                #pragma unroll
                for (int q = 0; q < 16; q++) {
                    float4 aa = w4[q], cc = h4[q];
                    s += aa.x * cc.x + aa.y * cc.y + aa.z * cc.z + aa.w * cc.w;
                }
                s += __shfl_xor(s, 1); s += __shfl_xor(s, 2);
                if (ln == 0) st_pk(apk + a, ATAG, fmaxf(s + attn_b[a], 0.f));
            }
        }
        // ---- stage attn packets + wait img flags ----
        attn_s[tid] = poll_pk(apk + tid, ATAG);
        if (tid < 64) attn_s[256 + tid] = poll_pk(apk + 256 + tid, ATAG);
        if (tid < 64) {
            while (__hip_atomic_load(imgf + tid, __ATOMIC_RELAXED, __HIP_MEMORY_SCOPE_AGENT) != MAGIC) {}
        }
        __builtin_amdgcn_fence(__ATOMIC_ACQUIRE, "agent");
        __syncthreads();

        // ---- redundant av (each GRU block computes all 680) ----
        for (int o = tid; o < 680; o += 256) {
            int k = o / 136, rem = o - k * 136;
            const float* ag = attn_s + k * 64;
            const float* ip = img + rem;
            float s = 0.f;
            #pragma unroll 8
            for (int c = 0; c < 64; c++) s = fmaf(ag[c], ip[c * 136], s);
            av_s[o] = s;
        }
        __syncthreads();

        // ---- feat rows [b*32,+32): 8 threads/row ----
        {
            int lr = tid >> 3, ln = tid & 7;
            int fr = b * 32 + lr;
            const float4* w4 = reinterpret_cast<const float4*>(lin_w + fr * 680);
            const float4* a4 = reinterpret_cast<const float4*>(av_s);
            float s = 0.f;
            for (int c = ln; c < 170; c += 8) {
                float4 a = w4[c], cc = a4[c];
                s += a.x * cc.x + a.y * cc.y + a.z * cc.z + a.w * cc.w;
            }
            s += __shfl_xor(s, 1); s += __shfl_xor(s, 2); s += __shfl_xor(s, 4);
            if (ln == 0) st_pk(fpk + fr, FTAG, fmaxf(s + lin_b[fr], 0.f));
        }

        // ---- block 0: LSTM cell + heads + scratch self-clean ----
        if (b == 0) {
            float ig = poll_pk(lpk + tid, LTAG);
            float fg = poll_pk(lpk + 256 + tid, LTAG);
            float gg = poll_pk(lpk + 512 + tid, LTAG);
            float og = poll_pk(lpk + 768 + tid, LTAG);
            float cc = sigmf(fg) * cx[tid] + sigmf(ig) * tanhf(gg);
            float hh = sigmf(og) * tanhf(cc);
            out[260 + tid] = cc;   // c2
            out[4 + tid] = hh;     // h2x
            f2_s[tid] = hh;
            if (tid < 32) f2_s[256 + tid] = time_emb[tx[0] * 32 + tid];
            __syncthreads();
            int wv = tid >> 6, ln = tid & 63;
            const float* wr = (wv == 0) ? critic_w : (actor_w + (wv - 1) * 288);
            float p = 0.f;
            for (int i = ln; i < 288; i += 64) p = fmaf(f2_s[i], wr[i], p);
            #pragma unroll
            for (int off = 32; off >= 1; off >>= 1) p += __shfl_down(p, off);
            if (ln == 0) out[wv] = p + ((wv == 0) ? critic_b[0] : actor_b[wv - 1]);
            // self-clean: all pollers of every flag/packet have provably passed
            // (transitively ordered before lpk completion).
            __syncthreads();
            for (int i = tid; i < 544; i += 256) flags[i] = 0;
            for (int i = tid; i < 18 * 256; i += 256) hpk[i] = 0ull;
            for (int i = tid; i < 320; i += 256) apk[i] = 0ull;
            if (tid < 256) fpk[tid] = 0ull;
            for (int i = tid; i < 1024; i += 256) lpk[i] = 0ull;
        }
    } else {
        // ============== worker path: conv1 -> conv2 -> conv3 -> LSTM rows ==============
        const int wb = b - NGRU;   // 0..239

        // ---- conv1: 1536 (co, 256px-chunk) tiles ----
        for (int tile = wb; tile < 1536; tile += NWRK) {
            int co = tile / 12, chunk = tile % 12;
            __syncthreads();
            if (tid < 192) ws[tid] = conv1_w[co * 192 + tid];
            __syncthreads();
            int pix = chunk * 256 + tid;
            if (pix < 3034) {
                int oh = pix / 74, ow = pix % 74;
                const float* xp = x + oh * 4 * 300 + ow * 4;
                float acc = conv1_b[co];
                #pragma unroll
                for (int ci = 0; ci < 3; ci++) {
                    #pragma unroll
                    for (int kh = 0; kh < 8; kh++) {
                        const float* row = xp + ci * (168 * 300) + kh * 300;
                        const float* wr = ws + ci * 64 + kh * 8;
                        float4 q0 = *reinterpret_cast<const float4*>(row);
                        float4 q1 = *reinterpret_cast<const float4*>(row + 4);
                        acc += q0.x * wr[0] + q0.y * wr[1] + q0.z * wr[2] + q0.w * wr[3]
                             + q1.x * wr[4] + q1.y * wr[5] + q1.z * wr[6] + q1.w * wr[7];
                    }
                }
                st_agent(c1o + co * 3034 + pix, fmaxf(acc, 0.f));
            }
        }
        __syncthreads();
        if (tid == 0) st_flag(c1f + wb);
        poll_flags(c1f, NWRK, tid);

        // ---- conv2: 192 (co, 256px-chunk) tiles, one per block ----
        for (int tile = wb; tile < 192; tile += NWRK) {
            int co = tile / 3, chunk = tile % 3;
            __syncthreads();
            for (int i = tid; i < 2048; i += 256) ws[i] = conv2_w[co * 2048 + i];
            __syncthreads();
            int pix = chunk * 256 + tid;
            if (pix < 684) {
                int oh = pix / 36, ow = pix % 36;
                const float* base = c1o + oh * 2 * 74 + ow * 2;
                float acc = conv2_b[co];
                #pragma unroll 4
                for (int ci = 0; ci < 128; ci++) {
                    const float* ip = base + ci * 3034;
                    const float* wc = ws + ci * 16;
                    #pragma unroll
                    for (int kh = 0; kh < 4; kh++) {
                        const float* row = ip + kh * 74;
                        const float* wr = wc + kh * 4;
                        float2 a0 = *reinterpret_cast<const float2*>(row);
                        float2 a1 = *reinterpret_cast<const float2*>(row + 2);
                        acc += a0.x * wr[0] + a0.y * wr[1] + a1.x * wr[2] + a1.y * wr[3];
                    }
                }
                st_agent(c2o + co * 684 + pix, fmaxf(acc, 0.f));
            }
        }
        __syncthreads();
        if (tid == 0) st_flag(c2f + wb);

        if (wb < 64) {
            poll_flags(c2f, NWRK, tid);
            // ---- conv3: co = wb ----
            {
                int co = wb;
                for (int i = tid; i < 1024; i += 256) ws[i] = conv3_w[co * 1024 + i];
                __syncthreads();
                if (tid < 136) {
                    int oh = tid / 17, ow = tid % 17;
                    const float* base = c2o + oh * 2 * 36 + ow * 2;
                    float acc = conv3_b[co];
                    #pragma unroll 4
                    for (int ci = 0; ci < 64; ci++) {
                        const float* ip = base + ci * 684;
                        const float* wc = ws + ci * 16;
                        #pragma unroll
                        for (int kh = 0; kh < 4; kh++) {
                            const float* row = ip + kh * 36;
                            const float* wr = wc + kh * 4;
                            float2 a0 = *reinterpret_cast<const float2*>(row);
                            float2 a1 = *reinterpret_cast<const float2*>(row + 2);
                            acc += a0.x * wr[0] + a0.y * wr[1] + a1.x * wr[2] + a1.y * wr[3];
                        }
                    }
                    st_agent(img + co * 136 + tid, fmaxf(acc, 0.f));
                }
                __syncthreads();
                if (tid == 0) st_flag(imgf + wb);
            }
            // ---- stage feat packets, then LSTM rows [wb*16,+16), 16 thr/row ----
            feat_ls[tid] = poll_pk(fpk + tid, FTAG);
            __syncthreads();
            {
                int lr = tid >> 4, ln = tid & 15;
                int r = wb * 16 + lr;
                const float4* wi4 = reinterpret_cast<const float4*>(lstm_wih + r * 256);
                const float4* wh4 = reinterpret_cast<const float4*>(lstm_whh + r * 256);
                const float4* f4 = reinterpret_cast<const float4*>(feat_ls);
                const float4* x4 = reinterpret_cast<const float4*>(hx);
                float s = 0.f;
                #pragma unroll
                for (int q = 0; q < 4; q++) {
                    float4 a = wi4[ln * 4 + q], c = f4[ln * 4 + q];
                    s += a.x * c.x + a.y * c.y + a.z * c.z + a.w * c.w;
                    float4 dd = wh4[ln * 4 + q], e = x4[ln * 4 + q];
                    s += dd.x * e.x + dd.y * e.y + dd.z * e.z + dd.w * e.w;
                }
                s += __shfl_xor(s, 1); s += __shfl_xor(s, 2);
                s += __shfl_xor(s, 4); s += __shfl_xor(s, 8);
                if (ln == 0) st_pk(lpk + r, LTAG, s + lstm_bih[r] + lstm_bhh[r]);
            }
        }
    }
}

extern "C" void kernel_launch(void* const* d_in, const int* in_sizes, int n_in,
                              void* d_out, int out_size, void* d_ws, size_t ws_size,
                              hipStream_t stream) {
    const float* x        = (const float*)d_in[0];
    const int*   inst     = (const int*)d_in[1];
    const int*   tx       = (const int*)d_in[2];
    const float* hx       = (const float*)d_in[3];
    const float* cx       = (const float*)d_in[4];
    const float* conv1_w  = (const float*)d_in[5];
    const float* conv1_b  = (const float*)d_in[6];
    const float* conv2_w  = (const float*)d_in[7];
    const float* conv2_b  = (const float*)d_in[8];
    const float* conv3_w  = (const float*)d_in[9];
    const float* conv3_b  = (const float*)d_in[10];
    const float* emb      = (const float*)d_in[11];
    const float* gru_wih  = (const float*)d_in[12];
    const float* gru_whh  = (const float*)d_in[13];
    const float* gru_bih  = (const float*)d_in[14];
    const float* gru_bhh  = (const float*)d_in[15];
    const float* attn_w   = (const float*)d_in[16];
    const float* attn_b   = (const float*)d_in[17];
    const float* time_emb = (const float*)d_in[18];
    const float* lin_w    = (const float*)d_in[19];
    const float* lin_b    = (const float*)d_in[20];
    const float* lstm_wih = (const float*)d_in[21];
    const float* lstm_whh = (const float*)d_in[22];
    const float* lstm_bih = (const float*)d_in[23];
    const float* lstm_bhh = (const float*)d_in[24];
    const float* critic_w = (const float*)d_in[25];
    const float* critic_b = (const float*)d_in[26];
    const float* actor_w  = (const float*)d_in[27];
    const float* actor_b  = (const float*)d_in[28];

    float* wsf = (float*)d_ws;
    float* c1o  = wsf;                    // [388352]
    float* c2o  = wsf + 388352;           // [43776]
    float* img  = wsf + 432128;           // [8704]  -> ends 440832
    unsigned long long* hpk = (unsigned long long*)(wsf + 440832); // [18*256] u64 (9216 floats)
    unsigned long long* apk = (unsigned long long*)(wsf + 450048); // [320] u64 (640 floats)
    unsigned long long* fpk = (unsigned long long*)(wsf + 450688); // [256] u64 (512 floats)
    unsigned long long* lpk = (unsigned long long*)(wsf + 451200); // [1024] u64 (2048 floats)
    int* flags = (int*)(wsf + 453248);    // [544] ints
    float* out = (float*)d_out;           // [516] = critic(1)+actor(3)+h2x(256)+c2(256)

    mega_k<<<NBLK, 256, 0, stream>>>(x, inst, tx, hx, cx,
                                     conv1_w, conv1_b, conv2_w, conv2_b, conv3_w, conv3_b,
                                     emb, gru_wih, gru_whh, gru_bih, gru_bhh,
                                     attn_w, attn_b, time_emb, lin_w, lin_b,
                                     lstm_wih, lstm_whh, lstm_bih, lstm_bhh,
                                     critic_w, critic_b, actor_w, actor_b,
                                     c1o, c2o, img, hpk, apk, fpk, lpk,
                                     flags, out);
}

// Round 9
// 201.649 us; speedup vs baseline: 3.6087x; 1.0235x over previous
//
#include <hip/hip_runtime.h>
#include <math.h>

#define MAGIC 0x3C96A5F1
#define NGRU 8
#define NWRK 240
#define NBLK (NGRU + NWRK)   // 248 blocks, ~122KB LDS -> 1 block/CU, all co-resident
#define WSTR 260             // whh LDS row stride (floats)
#define ATAG 7u
#define FTAG 9u
#define LTAG 11u

__device__ __forceinline__ float sigmf(float x) { return 1.0f / (1.0f + expf(-x)); }

__device__ __forceinline__ void st_agent(float* p, float v) {
    __hip_atomic_store(p, v, __ATOMIC_RELAXED, __HIP_MEMORY_SCOPE_AGENT);
}
__device__ __forceinline__ void st_flag(int* p) {
    __hip_atomic_store(p, MAGIC, __ATOMIC_RELEASE, __HIP_MEMORY_SCOPE_AGENT);
}
// sleepy flag poll: for throughput barriers (reduces LLC poll-storm contention)
__device__ __forceinline__ void poll_flags_s(const int* f, int n, int tid) {
    if (tid < n) {
        while (__hip_atomic_load(f + tid, __ATOMIC_RELAXED, __HIP_MEMORY_SCOPE_AGENT) != MAGIC)
            __builtin_amdgcn_s_sleep(2);
    }
    __builtin_amdgcn_fence(__ATOMIC_ACQUIRE, "agent");
    __syncthreads();
}
// single-word publish: (tag<<32)|bits — value rides with the tag, no fence needed
__device__ __forceinline__ void st_pk(unsigned long long* p, unsigned tag, float v) {
    __hip_atomic_store(p, ((unsigned long long)tag << 32) | (unsigned long long)__float_as_uint(v),
                       __ATOMIC_RELAXED, __HIP_MEMORY_SCOPE_AGENT);
}
__device__ __forceinline__ float poll_pk(const unsigned long long* p, unsigned tag) {
    unsigned long long v;
    do { v = __hip_atomic_load(p, __ATOMIC_RELAXED, __HIP_MEMORY_SCOPE_AGENT); }
    while ((unsigned)(v >> 32) != tag);
    return __uint_as_float((unsigned)(v & 0xffffffffu));
}
// light-sleep packet poll: latency-tolerant mass polls (64 blocks on fpk)
__device__ __forceinline__ float poll_pk_s(const unsigned long long* p, unsigned tag) {
    unsigned long long v = __hip_atomic_load(p, __ATOMIC_RELAXED, __HIP_MEMORY_SCOPE_AGENT);
    while ((unsigned)(v >> 32) != tag) {
        __builtin_amdgcn_s_sleep(1);
        v = __hip_atomic_load(p, __ATOMIC_RELAXED, __HIP_MEMORY_SCOPE_AGENT);
    }
    return __uint_as_float((unsigned)(v & 0xffffffffu));
}

__global__ __launch_bounds__(256) void mega_k(
    const float* __restrict__ x, const int* __restrict__ inst, const int* __restrict__ tx,
    const float* __restrict__ hx, const float* __restrict__ cx,
    const float* __restrict__ conv1_w, const float* __restrict__ conv1_b,
    const float* __restrict__ conv2_w, const float* __restrict__ conv2_b,
    const float* __restrict__ conv3_w, const float* __restrict__ conv3_b,
    const float* __restrict__ emb,
    const float* __restrict__ wih, const float* __restrict__ whh,
    const float* __restrict__ bih, const float* __restrict__ bhh,
    const float* __restrict__ attn_w, const float* __restrict__ attn_b,
    const float* __restrict__ time_emb,
    const float* __restrict__ lin_w, const float* __restrict__ lin_b,
    const float* __restrict__ lstm_wih, const float* __restrict__ lstm_whh,
    const float* __restrict__ lstm_bih, const float* __restrict__ lstm_bhh,
    const float* __restrict__ critic_w, const float* __restrict__ critic_b,
    const float* __restrict__ actor_w, const float* __restrict__ actor_b,
    float* __restrict__ c1o, float* __restrict__ c2o, float* __restrict__ img,
    unsigned long long* __restrict__ hpk,   // [18*256] (tag t+1)
    unsigned long long* __restrict__ apk,   // [320]
    unsigned long long* __restrict__ fpk,   // [256]
    unsigned long long* __restrict__ lpk,   // [1024]
    int* __restrict__ flags,                // c1f[240] c2f[240] imgf[64]
    float* __restrict__ out) {

    int* c1f  = flags;
    int* c2f  = flags + 240;
    int* imgf = flags + 480;

    __shared__ __align__(16) float whh_s[96 * WSTR]; // 97.5 KB; reused for lin_w at tail
    __shared__ float gi_s[18 * 96];
    __shared__ float wt_all[18 * 32];
    __shared__ float bhh_s[96];
    __shared__ __align__(16) float h_s[256];
    __shared__ __align__(16) float attn_s[320];
    __shared__ __align__(16) float av_s[680];
    __shared__ __align__(16) float f2_s[288];
    __shared__ __align__(16) float ws[2048];      // conv weight staging (workers)
    __shared__ __align__(16) float feat_ls[256];  // feat staged (workers)

    const int tid = threadIdx.x;
    const int b = blockIdx.x;

    if (b < NGRU) {
        // ============== GRU path: block owns h-dims [b*32, b*32+32) ==============
        const int d = tid >> 3;          // dim within slice
        const int ch = tid & 7;          // 8 col-chunks of 32
        const int dimg = b * 32 + d;

        // stage whh rows (r,z,g of my dims) into LDS, coalesced float4
        for (int i = tid; i < 96 * 64; i += 256) {
            int lr = i >> 6, q = i & 63;
            int gr = (lr >> 5) * 256 + b * 32 + (lr & 31);
            float4 v = *reinterpret_cast<const float4*>(whh + gr * 256 + q * 4);
            *reinterpret_cast<float4*>(&whh_s[lr * WSTR + q * 4]) = v;
        }
        for (int i = tid; i < 18 * 32; i += 256) wt_all[i] = emb[inst[i >> 5] * 32 + (i & 31)];
        if (tid < 96) bhh_s[tid] = bhh[(tid >> 5) * 256 + b * 32 + (tid & 31)];
        h_s[tid] = 0.0f;
        __syncthreads();

        // warm this block's attn_w rows into XCD L2 (overlaps gi compute below)
        float wsum = 0.f;
        {
            const float4* aw = reinterpret_cast<const float4*>(attn_w + b * 40 * 256);
            #pragma unroll
            for (int i = 0; i < 10; i++) {
                float4 v = aw[tid + i * 256];
                wsum += v.x + v.y + v.z + v.w;
            }
        }
        asm volatile("" :: "v"(wsum));   // keep loads alive

        // gi precompute (h-independent): gi_s[t*96 + gate*32 + j]
        for (int u = tid; u < 18 * 96; u += 256) {
            int t = u / 96, r = u % 96;
            int R = (r >> 5) * 256 + b * 32 + (r & 31);
            const float4* w4 = reinterpret_cast<const float4*>(wih + R * 32);
            const float4* e4 = reinterpret_cast<const float4*>(wt_all + t * 32);
            float s = 0.f;
            #pragma unroll
            for (int q = 0; q < 8; q++) {
                float4 a = w4[q], c = e4[q];
                s += a.x * c.x + a.y * c.y + a.z * c.z + a.w * c.w;
            }
            gi_s[u] = s + bih[R];
        }
        __syncthreads();

        // ---- 18 GRU steps: one packet RTT each ----
        for (int t = 0; t < 18; t++) {
            const float4* hr4 = reinterpret_cast<const float4*>(h_s + ch * 32);
            const float4* w0 = reinterpret_cast<const float4*>(&whh_s[d * WSTR + ch * 32]);
            const float4* w1 = reinterpret_cast<const float4*>(&whh_s[(32 + d) * WSTR + ch * 32]);
            const float4* w2 = reinterpret_cast<const float4*>(&whh_s[(64 + d) * WSTR + ch * 32]);
            float p0 = 0.f, p1 = 0.f, p2 = 0.f;
            #pragma unroll
            for (int j = 0; j < 8; j++) {
                float4 c = hr4[j];
                float4 a0 = w0[j], a1 = w1[j], a2 = w2[j];
                p0 += a0.x * c.x + a0.y * c.y + a0.z * c.z + a0.w * c.w;
                p1 += a1.x * c.x + a1.y * c.y + a1.z * c.z + a1.w * c.w;
                p2 += a2.x * c.x + a2.y * c.y + a2.z * c.z + a2.w * c.w;
            }
            p0 += __shfl_xor(p0, 1); p0 += __shfl_xor(p0, 2); p0 += __shfl_xor(p0, 4);
            p1 += __shfl_xor(p1, 1); p1 += __shfl_xor(p1, 2); p1 += __shfl_xor(p1, 4);
            p2 += __shfl_xor(p2, 1); p2 += __shfl_xor(p2, 2); p2 += __shfl_xor(p2, 4);
            if (ch == 0) {
                float ghr = p0 + bhh_s[d];
                float ghz = p1 + bhh_s[32 + d];
                float ghg = p2 + bhh_s[64 + d];
                float rr = sigmf(gi_s[t * 96 + d] + ghr);
                float zz = sigmf(gi_s[t * 96 + 32 + d] + ghz);
                float gg = tanhf(gi_s[t * 96 + 64 + d] + rr * ghg);
                float hn = (1.f - zz) * gg + zz * h_s[dimg];
                st_pk(hpk + t * 256 + dimg, (unsigned)(t + 1), hn);
            }
            float hv = poll_pk(hpk + t * 256 + tid, (unsigned)(t + 1));
            __syncthreads();          // all matvec reads of old h_s done
            h_s[tid] = hv;
            __syncthreads();
        }

        // ---- attention rows [b*40, b*40+40): 4 threads/row (attn_w L2-warm) ----
        {
            int lr = tid >> 2, ln = tid & 3;
            if (lr < 40) {
                int a = b * 40 + lr;
                const float4* w4 = reinterpret_cast<const float4*>(attn_w + a * 256 + ln * 64);
                const float4* h4 = reinterpret_cast<const float4*>(h_s + ln * 64);
                float s = 0.f;
                #pragma unroll
                for (int q = 0; q < 16; q++) {
                    float4 aa = w4[q], cc = h4[q];
                    s += aa.x * cc.x + aa.y * cc.y + aa.z * cc.z + aa.w * cc.w;
                }
                s += __shfl_xor(s, 1); s += __shfl_xor(s, 2);
                if (ln == 0) st_pk(apk + a, ATAG, fmaxf(s + attn_b[a], 0.f));
            }
        }
        // ---- stage my lin_w rows into dead whh_s (hides fetch under apk RTT) ----
        {
            const float4* lw = reinterpret_cast<const float4*>(lin_w + b * 32 * 680);
            float4* dst = reinterpret_cast<float4*>(whh_s);
            for (int i = tid; i < 32 * 170; i += 256) dst[i] = lw[i];
        }
        // ---- stage attn packets + wait img flags ----
        attn_s[tid] = poll_pk(apk + tid, ATAG);
        if (tid < 64) attn_s[256 + tid] = poll_pk(apk + 256 + tid, ATAG);
        if (tid < 64) {
            while (__hip_atomic_load(imgf + tid, __ATOMIC_RELAXED, __HIP_MEMORY_SCOPE_AGENT) != MAGIC) {}
        }
        __builtin_amdgcn_fence(__ATOMIC_ACQUIRE, "agent");
        __syncthreads();

        // ---- redundant av (each GRU block computes all 680) ----
        for (int o = tid; o < 680; o += 256) {
            int k = o / 136, rem = o - k * 136;
            const float* ag = attn_s + k * 64;
            const float* ip = img + rem;
            float s = 0.f;
            #pragma unroll 8
            for (int c = 0; c < 64; c++) s = fmaf(ag[c], ip[c * 136], s);
            av_s[o] = s;
        }
        __syncthreads();

        // ---- feat rows [b*32,+32): 8 threads/row, lin_w from LDS ----
        {
            int lr = tid >> 3, ln = tid & 7;
            int fr = b * 32 + lr;
            const float4* w4 = reinterpret_cast<const float4*>(whh_s + lr * 680);
            const float4* a4 = reinterpret_cast<const float4*>(av_s);
            float s = 0.f;
            for (int c = ln; c < 170; c += 8) {
                float4 a = w4[c], cc = a4[c];
                s += a.x * cc.x + a.y * cc.y + a.z * cc.z + a.w * cc.w;
            }
            s += __shfl_xor(s, 1); s += __shfl_xor(s, 2); s += __shfl_xor(s, 4);
            if (ln == 0) st_pk(fpk + fr, FTAG, fmaxf(s + lin_b[fr], 0.f));
        }

        // ---- block 0: LSTM cell + heads + scratch self-clean ----
        if (b == 0) {
            float ig = poll_pk(lpk + tid, LTAG);
            float fg = poll_pk(lpk + 256 + tid, LTAG);
            float gg = poll_pk(lpk + 512 + tid, LTAG);
            float og = poll_pk(lpk + 768 + tid, LTAG);
            float cc = sigmf(fg) * cx[tid] + sigmf(ig) * tanhf(gg);
            float hh = sigmf(og) * tanhf(cc);
            out[260 + tid] = cc;   // c2
            out[4 + tid] = hh;     // h2x
            f2_s[tid] = hh;
            if (tid < 32) f2_s[256 + tid] = time_emb[tx[0] * 32 + tid];
            __syncthreads();
            int wv = tid >> 6, ln = tid & 63;
            const float* wr = (wv == 0) ? critic_w : (actor_w + (wv - 1) * 288);
            float p = 0.f;
            for (int i = ln; i < 288; i += 64) p = fmaf(f2_s[i], wr[i], p);
            #pragma unroll
            for (int off = 32; off >= 1; off >>= 1) p += __shfl_down(p, off);
            if (ln == 0) out[wv] = p + ((wv == 0) ? critic_b[0] : actor_b[wv - 1]);
            // self-clean: all pollers of every flag/packet have provably passed
            __syncthreads();
            for (int i = tid; i < 544; i += 256) flags[i] = 0;
            for (int i = tid; i < 18 * 256; i += 256) hpk[i] = 0ull;
            for (int i = tid; i < 320; i += 256) apk[i] = 0ull;
            if (tid < 256) fpk[tid] = 0ull;
            for (int i = tid; i < 1024; i += 256) lpk[i] = 0ull;
        }
    } else {
        // ============== worker path: conv1 -> conv2 -> conv3 -> LSTM rows ==============
        const int wb = b - NGRU;   // 0..239

        // ---- conv1: 1536 (co, 256px-chunk) tiles ----
        for (int tile = wb; tile < 1536; tile += NWRK) {
            int co = tile / 12, chunk = tile % 12;
            __syncthreads();
            if (tid < 192) ws[tid] = conv1_w[co * 192 + tid];
            __syncthreads();
            int pix = chunk * 256 + tid;
            if (pix < 3034) {
                int oh = pix / 74, ow = pix % 74;
                const float* xp = x + oh * 4 * 300 + ow * 4;
                float acc = conv1_b[co];
                #pragma unroll
                for (int ci = 0; ci < 3; ci++) {
                    #pragma unroll
                    for (int kh = 0; kh < 8; kh++) {
                        const float* row = xp + ci * (168 * 300) + kh * 300;
                        const float* wr = ws + ci * 64 + kh * 8;
                        float4 q0 = *reinterpret_cast<const float4*>(row);
                        float4 q1 = *reinterpret_cast<const float4*>(row + 4);
                        acc += q0.x * wr[0] + q0.y * wr[1] + q0.z * wr[2] + q0.w * wr[3]
                             + q1.x * wr[4] + q1.y * wr[5] + q1.z * wr[6] + q1.w * wr[7];
                    }
                }
                st_agent(c1o + co * 3034 + pix, fmaxf(acc, 0.f));
            }
        }
        __syncthreads();
        if (tid == 0) st_flag(c1f + wb);
        poll_flags_s(c1f, NWRK, tid);

        // ---- conv2: 192 (co, 256px-chunk) tiles ----
        for (int tile = wb; tile < 192; tile += NWRK) {
            int co = tile / 3, chunk = tile % 3;
            __syncthreads();
            for (int i = tid; i < 2048; i += 256) ws[i] = conv2_w[co * 2048 + i];
            __syncthreads();
            int pix = chunk * 256 + tid;
            if (pix < 684) {
                int oh = pix / 36, ow = pix % 36;
                const float* base = c1o + oh * 2 * 74 + ow * 2;
                float acc = conv2_b[co];
                #pragma unroll 4
                for (int ci = 0; ci < 128; ci++) {
                    const float* ip = base + ci * 3034;
                    const float* wc = ws + ci * 16;
                    #pragma unroll
                    for (int kh = 0; kh < 4; kh++) {
                        const float* row = ip + kh * 74;
                        const float* wr = wc + kh * 4;
                        float2 a0 = *reinterpret_cast<const float2*>(row);
                        float2 a1 = *reinterpret_cast<const float2*>(row + 2);
                        acc += a0.x * wr[0] + a0.y * wr[1] + a1.x * wr[2] + a1.y * wr[3];
                    }
                }
                st_agent(c2o + co * 684 + pix, fmaxf(acc, 0.f));
            }
        }
        __syncthreads();
        if (tid == 0) st_flag(c2f + wb);

        if (wb < 64) {
            poll_flags_s(c2f, NWRK, tid);
            // ---- conv3: co = wb ----
            {
                int co = wb;
                for (int i = tid; i < 1024; i += 256) ws[i] = conv3_w[co * 1024 + i];
                __syncthreads();
                if (tid < 136) {
                    int oh = tid / 17, ow = tid % 17;
                    const float* base = c2o + oh * 2 * 36 + ow * 2;
                    float acc = conv3_b[co];
                    #pragma unroll 4
                    for (int ci = 0; ci < 64; ci++) {
                        const float* ip = base + ci * 684;
                        const float* wc = ws + ci * 16;
                        #pragma unroll
                        for (int kh = 0; kh < 4; kh++) {
                            const float* row = ip + kh * 36;
                            const float* wr = wc + kh * 4;
                            float2 a0 = *reinterpret_cast<const float2*>(row);
                            float2 a1 = *reinterpret_cast<const float2*>(row + 2);
                            acc += a0.x * wr[0] + a0.y * wr[1] + a1.x * wr[2] + a1.y * wr[3];
                        }
                    }
                    st_agent(img + co * 136 + tid, fmaxf(acc, 0.f));
                }
                __syncthreads();
                if (tid == 0) st_flag(imgf + wb);
            }
            // ---- LSTM prep BEFORE fpk wait: wi rows -> regs, wh·hx partial ----
            int lr = tid >> 4, ln = tid & 15;
            int r = wb * 16 + lr;
            const float4* wi4 = reinterpret_cast<const float4*>(lstm_wih + r * 256);
            const float4* wh4 = reinterpret_cast<const float4*>(lstm_whh + r * 256);
            const float4* x4 = reinterpret_cast<const float4*>(hx);
            float4 wi0 = wi4[ln * 4 + 0], wi1 = wi4[ln * 4 + 1];
            float4 wi2 = wi4[ln * 4 + 2], wi3 = wi4[ln * 4 + 3];
            float s = 0.f;
            #pragma unroll
            for (int q = 0; q < 4; q++) {
                float4 dd = wh4[ln * 4 + q], e = x4[ln * 4 + q];
                s += dd.x * e.x + dd.y * e.y + dd.z * e.z + dd.w * e.w;
            }
            float bsum = lstm_bih[r] + lstm_bhh[r];
            // ---- poll feat (light sleep), finish with registered wi ----
            feat_ls[tid] = poll_pk_s(fpk + tid, FTAG);
            __syncthreads();
            const float4* f4 = reinterpret_cast<const float4*>(feat_ls);
            float4 c0 = f4[ln * 4 + 0], c1 = f4[ln * 4 + 1];
            float4 c2 = f4[ln * 4 + 2], c3 = f4[ln * 4 + 3];
            s += wi0.x * c0.x + wi0.y * c0.y + wi0.z * c0.z + wi0.w * c0.w;
            s += wi1.x * c1.x + wi1.y * c1.y + wi1.z * c1.z + wi1.w * c1.w;
            s += wi2.x * c2.x + wi2.y * c2.y + wi2.z * c2.z + wi2.w * c2.w;
            s += wi3.x * c3.x + wi3.y * c3.y + wi3.z * c3.z + wi3.w * c3.w;
            s += __shfl_xor(s, 1); s += __shfl_xor(s, 2);
            s += __shfl_xor(s, 4); s += __shfl_xor(s, 8);
            if (ln == 0) st_pk(lpk + r, LTAG, s + bsum);
        }
    }
}

extern "C" void kernel_launch(void* const* d_in, const int* in_sizes, int n_in,
                              void* d_out, int out_size, void* d_ws, size_t ws_size,
                              hipStream_t stream) {
    const float* x        = (const float*)d_in[0];
    const int*   inst     = (const int*)d_in[1];
    const int*   tx       = (const int*)d_in[2];
    const float* hx       = (const float*)d_in[3];
    const float* cx       = (const float*)d_in[4];
    const float* conv1_w  = (const float*)d_in[5];
    const float* conv1_b  = (const float*)d_in[6];
    const float* conv2_w  = (const float*)d_in[7];
    const float* conv2_b  = (const float*)d_in[8];
    const float* conv3_w  = (const float*)d_in[9];
    const float* conv3_b  = (const float*)d_in[10];
    const float* emb      = (const float*)d_in[11];
    const float* gru_wih  = (const float*)d_in[12];
    const float* gru_whh  = (const float*)d_in[13];
    const float* gru_bih  = (const float*)d_in[14];
    const float* gru_bhh  = (const float*)d_in[15];
    const float* attn_w   = (const float*)d_in[16];
    const float* attn_b   = (const float*)d_in[17];
    const float* time_emb = (const float*)d_in[18];
    const float* lin_w    = (const float*)d_in[19];
    const float* lin_b    = (const float*)d_in[20];
    const float* lstm_wih = (const float*)d_in[21];
    const float* lstm_whh = (const float*)d_in[22];
    const float* lstm_bih = (const float*)d_in[23];
    const float* lstm_bhh = (const float*)d_in[24];
    const float* critic_w = (const float*)d_in[25];
    const float* critic_b = (const float*)d_in[26];
    const float* actor_w  = (const float*)d_in[27];
    const float* actor_b  = (const float*)d_in[28];

    float* wsf = (float*)d_ws;
    float* c1o  = wsf;                    // [388352]
    float* c2o  = wsf + 388352;           // [43776]
    float* img  = wsf + 432128;           // [8704]  -> ends 440832
    unsigned long long* hpk = (unsigned long long*)(wsf + 440832); // [18*256] u64
    unsigned long long* apk = (unsigned long long*)(wsf + 450048); // [320] u64
    unsigned long long* fpk = (unsigned long long*)(wsf + 450688); // [256] u64
    unsigned long long* lpk = (unsigned long long*)(wsf + 451200); // [1024] u64
    int* flags = (int*)(wsf + 453248);    // [544] ints
    float* out = (float*)d_out;           // [516] = critic(1)+actor(3)+h2x(256)+c2(256)

    mega_k<<<NBLK, 256, 0, stream>>>(x, inst, tx, hx, cx,
                                     conv1_w, conv1_b, conv2_w, conv2_b, conv3_w, conv3_b,
                                     emb, gru_wih, gru_whh, gru_bih, gru_bhh,
                                     attn_w, attn_b, time_emb, lin_w, lin_b,
                                     lstm_wih, lstm_whh, lstm_bih, lstm_bhh,
                                     critic_w, critic_b, actor_w, actor_b,
                                     c1o, c2o, img, hpk, apk, fpk, lpk,
                                     flags, out);
}